// Round 6
// baseline (173.467 us; speedup 1.0000x reference)
//
#include <hip/hip_runtime.h>
#include <math.h>

// Problem constants (from reference setup_inputs)
#define BB 16
#define LL 64
#define FF 60
#define DD 256
#define UU 600
#define VV 10000
#define JMAX 10
#define MINL 4
#define EE 7           // MAX_LEN - MIN_LEN + 1
#define NEG (-1e9f)
#define TH 0.05f
#define BCAP 10240     // per-bucket record capacity (>= V)

// Workspace layout in u32/float units (ws_size ~256 MB per harness fill — ample).
#define UNT_OFF   0                         // unT[256][640]  (u padded 600->640)
#define WNT_OFF   163840                    // wnT[256][1024] (bl = b*64+l)
#define SIM_OFF   425984                    // sim[16][64][600]
#define CNT_OFF   1040384                   // uint cnt[8] (memset to 0)
#define SRT_OFF   1040392                   // records: 7 buckets x 10240 x 8 u32 (32B-aligned)
#define VAL_OFF   1613832                   // val[2][16][64][7]  (per v-half)
#define VOC_OFF   1628168                   // int voc[2][16][64][7]

// ---------------------------------------------------------------------------
// Fused prep: blocks [0,40) bucket-sort vocab records; blocks [40,446) embed.
// Record (32B): w0..w4 = 10 x u16 LDS indices (u*11+j), w5 = v, w6,w7 pad.
// Bucket e = vlen-4; position via device-scope atomicAdd (order-stability not
// needed: k_score's update is v-tie-aware).
__global__ __launch_bounds__(256) void k_prep(const int* __restrict__ seg,
                                              const int* __restrict__ vlen,
                                              const float* __restrict__ x,
                                              const float* __restrict__ uf,
                                              const float* __restrict__ W,
                                              unsigned int* __restrict__ cnt,
                                              unsigned int* __restrict__ srt,
                                              float* __restrict__ unT,
                                              float* __restrict__ wnT) {
    int blk = blockIdx.x;
    if (blk < 40) {
        int v = blk * 256 + threadIdx.x;
        if (v >= VV) return;
        const int* s = seg + v * JMAX;
        unsigned int t[10];
#pragma unroll
        for (int j = 0; j < JMAX; ++j) t[j] = (unsigned int)(s[j] * 11 + j);
        int e = vlen[v] - MINL;                       // 0..6
        unsigned int pos = atomicAdd(&cnt[e], 1u);
        unsigned int* dst = srt + ((size_t)e * BCAP + pos) * 8;
        uint4 qa, qb;
        qa.x = t[0] | (t[1] << 16);
        qa.y = t[2] | (t[3] << 16);
        qa.z = t[4] | (t[5] << 16);
        qa.w = t[6] | (t[7] << 16);
        qb.x = t[8] | (t[9] << 16);
        qb.y = (unsigned int)v;
        qb.z = 0; qb.w = 0;
        ((uint4*)dst)[0] = qa;
        ((uint4*)dst)[1] = qb;
    } else {
        // embed: wave w of block handles row (blk-40)*4 + w; 1624 rows total.
        int w = threadIdx.x >> 6;
        int lane = threadIdx.x & 63;
        int id = (blk - 40) * 4 + w;
        const float* row;
        float* outB;
        int stride, col;
        if (id < UU) { row = uf + id * FF; outB = unT; stride = 640;  col = id; }
        else { int bl = id - UU; row = x + bl * FF; outB = wnT; stride = 1024; col = bl; }

        float r0 = 0.f, r1 = 0.f, r2 = 0.f, r3 = 0.f;
#pragma unroll 4
        for (int f = 0; f < FF; ++f) {
            float xv = row[f];  // wave-uniform broadcast load
            r0 += xv * W[f * DD + lane];
            r1 += xv * W[f * DD + lane + 64];
            r2 += xv * W[f * DD + lane + 128];
            r3 += xv * W[f * DD + lane + 192];
        }
        float ss = r0 * r0 + r1 * r1 + r2 * r2 + r3 * r3;
#pragma unroll
        for (int m = 32; m > 0; m >>= 1) ss += __shfl_xor(ss, m, 64);
        float inv = 1.0f / (sqrtf(ss) + 1e-8f);   // matches ref x/(norm+1e-8)
        outB[(lane      ) * stride + col] = r0 * inv;
        outB[(lane +  64) * stride + col] = r1 * inv;
        outB[(lane + 128) * stride + col] = r2 * inv;
        outB[(lane + 192) * stride + col] = r3 * inv;
    }
}

// ---------------------------------------------------------------------------
// sim[b][l][u] = wn[bl] . un[u].  512 blocks = (b, l-quad, u-half), 320
// threads. Thread tile: 4l x 1u; wn read as wave-uniform float4 per d.
// unT L2 traffic ~168 MB total (~5 us floor at 35 TB/s).
__global__ __launch_bounds__(320) void k_sim(const float* __restrict__ unT,
                                             const float* __restrict__ wnT,
                                             float* __restrict__ sim) {
    int blk = blockIdx.x;
    int b  = blk >> 5;
    int r  = blk & 31;
    int l0 = (r >> 1) * 4;
    int uh = r & 1;
    int bl0 = b * 64 + l0;
    int u = uh * 320 + threadIdx.x;     // < 640 (unT padded; stores guarded)

    float a0 = 0.f, a1 = 0.f, a2 = 0.f, a3 = 0.f;
#pragma unroll 8
    for (int d = 0; d < DD; ++d) {
        float4 wv = *(const float4*)(wnT + d * 1024 + bl0);  // uniform 16B
        float v  = unT[d * 640 + u];
        a0 += wv.x * v;
        a1 += wv.y * v;
        a2 += wv.z * v;
        a3 += wv.w * v;
    }
    if (u < UU) {
        sim[(bl0 + 0) * UU + u] = a0;
        sim[(bl0 + 1) * UU + u] = a1;
        sim[(bl0 + 2) * UU + u] = a2;
        sim[(bl0 + 3) * UU + u] = a3;
    }
}

// ---------------------------------------------------------------------------
// Per-bucket pass with STATIC k: exactly K ds_read2-pairs per record, one
// tie-aware best update (handles unstable bucket order: equal score -> lower
// v wins, matching jnp.argmax first-index semantics).
template<int K>
__device__ __forceinline__ void bucket_pass(const unsigned int* __restrict__ srt,
                                            const float* __restrict__ lds,
                                            int e, int half, int n, int tid,
                                            float& s0, int& w0,
                                            float& s1, int& w1) {
    int n0 = n >> 1;
    int lo = half ? n0 : 0;
    int hi = half ? n : n0;
    for (int p = lo + tid; p < hi; p += 512) {
        const uint4* pp = (const uint4*)(srt + ((size_t)e * BCAP + p) * 8);
        uint4 qa = pp[0];
        uint4 qb = pp[1];
        unsigned int tw[5] = {qa.x, qa.y, qa.z, qa.w, qb.x};
        int v = (int)qb.y;
        float a0 = 0.f, a1 = 0.f;
#pragma unroll
        for (int j = 0; j < K; ++j) {
            int idx = (int)((tw[j >> 1] >> ((j & 1) * 16)) & 0xffffu);
            float x0 = lds[idx];
            float x1 = lds[idx + 1];
            a0 += x0;
            a1 += x1;
        }
        bool p0 = (a0 > s0) || (a0 == s0 && v < w0);
        bool p1 = (a1 > s1) || (a1 == s1 && v < w1);
        s0 = p0 ? a0 : s0;  w0 = p0 ? v : w0;
        s1 = p1 ? a1 : s1;  w1 = p1 ? v : w1;
    }
}

// ---------------------------------------------------------------------------
// Phase 3: 1024 blocks = (v-half, b, l-pair), 512 threads. Stage sim rows
// l0..l0+10 in LDS transposed [u][11] (stride 11, coprime with 32 banks).
// Then 7 static-k bucket passes over sorted records; raw-sum compares,
// normalize winner once at the end.
__global__ __launch_bounds__(512, 8) void k_score(const float* __restrict__ sim,
                                                  const unsigned int* __restrict__ srt,
                                                  const unsigned int* __restrict__ cnt,
                                                  const int* __restrict__ lengths,
                                                  float* __restrict__ val,
                                                  int* __restrict__ voc) {
    __shared__ float lds[UU * 11];   // 26.4 KB -> 4 blocks/CU (waves-capped)
    __shared__ float redS[14][8];    // e*2+dl in [0,14) x 8 waves
    __shared__ int   redV[14][8];

    int blk = blockIdx.x;
    int half = blk >> 9;
    int rest = blk & 511;
    int b  = rest >> 5;
    int l0 = (rest & 31) * 2;
    int tid = threadIdx.x;

    // Stage sim tile -> LDS transposed; rows >= L are the zero-pad region.
    for (int u = tid; u < UU; u += 512) {
#pragma unroll
        for (int r = 0; r < 11; ++r) {
            int m = l0 + r;
            lds[u * 11 + r] = (m < LL) ? sim[(b * 64 + m) * UU + u] : 0.0f;
        }
    }
    __syncthreads();

    int ne[EE];
#pragma unroll
    for (int e = 0; e < EE; ++e) ne[e] = (int)cnt[e];   // uniform, L2-cached

    float bS[EE][2];
    int   bV[EE][2];
#pragma unroll
    for (int e = 0; e < EE; ++e) {
        bS[e][0] = -1e30f; bS[e][1] = -1e30f;
        bV[e][0] = VV;     bV[e][1] = VV;
    }

    bucket_pass<4> (srt, lds, 0, half, ne[0], tid, bS[0][0], bV[0][0], bS[0][1], bV[0][1]);
    bucket_pass<5> (srt, lds, 1, half, ne[1], tid, bS[1][0], bV[1][0], bS[1][1], bV[1][1]);
    bucket_pass<6> (srt, lds, 2, half, ne[2], tid, bS[2][0], bV[2][0], bS[2][1], bV[2][1]);
    bucket_pass<7> (srt, lds, 3, half, ne[3], tid, bS[3][0], bV[3][0], bS[3][1], bV[3][1]);
    bucket_pass<8> (srt, lds, 4, half, ne[4], tid, bS[4][0], bV[4][0], bS[4][1], bV[4][1]);
    bucket_pass<9> (srt, lds, 5, half, ne[5], tid, bS[5][0], bV[5][0], bS[5][1], bV[5][1]);
    bucket_pass<10>(srt, lds, 6, half, ne[6], tid, bS[6][0], bV[6][0], bS[6][1], bV[6][1]);

    int w = tid >> 6, lane = tid & 63;
#pragma unroll
    for (int e = 0; e < EE; ++e) {
#pragma unroll
        for (int dl = 0; dl < 2; ++dl) {
            float s = bS[e][dl];
            int vv = bV[e][dl];
#pragma unroll
            for (int off = 32; off > 0; off >>= 1) {
                float os = __shfl_down(s, off, 64);
                int   ov = __shfl_down(vv, off, 64);
                if (os > s || (os == s && ov < vv)) { s = os; vv = ov; }
            }
            if (lane == 0) { redS[e * 2 + dl][w] = s; redV[e * 2 + dl][w] = vv; }
        }
    }
    __syncthreads();

    if (tid < 14) {   // only indices 0..13 of redS/redV are valid
        int e  = tid >> 1;
        int dl = tid & 1;
        float s = redS[tid][0];
        int  vv = redV[tid][0];
#pragma unroll
        for (int w2 = 1; w2 < 8; ++w2) {
            float os = redS[tid][w2];
            int   ov = redV[tid][w2];
            if (os > s || (os == s && ov < vv)) { s = os; vv = ov; }
        }
        int lg = l0 + dl;
        int k = e + MINL;
        bool viable = (lg + k - 1) < lengths[b];
        float sn = s / (float)k;   // normalize winner only (bit-same as ref a/k)
        int o = (half * BB * LL + b * 64 + lg) * EE + e;
        val[o] = viable ? sn : NEG;
        voc[o] = viable ? vv : 0;  // ref argmax of all-NEG = 0
    }
}

// ---------------------------------------------------------------------------
// Per-b: merge the two v-halves slot-wise (tie -> smaller voc = smaller v),
// then flat argmax over the 448 (l,e) slots (min flat index on ties),
// any_matched = merged max > THRESH. Outputs written as float32 values.
__global__ __launch_bounds__(512) void k_final(const float* __restrict__ val,
                                               const int* __restrict__ voc,
                                               float* __restrict__ out) {
    __shared__ float sS[8];
    __shared__ int   sI[8];
    __shared__ int   sV[8];
    __shared__ int   sA[8];
    int b = blockIdx.x;
    int t = threadIdx.x;
    float s = -3e38f;
    int idx = 1 << 30;
    int vc = 0;
    int any = 0;
    if (t < LL * EE) {
        int o0 = b * LL * EE + t;
        int o1 = BB * LL * EE + o0;
        float s0 = val[o0], s1 = val[o1];
        int   v0 = voc[o0], v1 = voc[o1];
        bool sel = (s1 > s0) || (s1 == s0 && v1 < v0);
        s  = sel ? s1 : s0;
        vc = sel ? v1 : v0;
        idx = t;
        any = (s > TH) ? 1 : 0;
    }
#pragma unroll
    for (int off = 32; off > 0; off >>= 1) {
        float os = __shfl_down(s, off, 64);
        int   oi = __shfl_down(idx, off, 64);
        int   ov = __shfl_down(vc, off, 64);
        int   oa = __shfl_down(any, off, 64);
        if (os > s || (os == s && oi < idx)) { s = os; idx = oi; vc = ov; }
        any |= oa;
    }
    int w = t >> 6, lane = t & 63;
    if (lane == 0) { sS[w] = s; sI[w] = idx; sV[w] = vc; sA[w] = any; }
    __syncthreads();
    if (t == 0) {
        for (int w2 = 1; w2 < 8; ++w2) {
            float os = sS[w2];
            int   oi = sI[w2];
            if (os > s || (os == s && oi < idx)) { s = os; idx = oi; vc = sV[w2]; }
            any |= sA[w2];
        }
        int start = idx / EE;
        int e = idx - start * EE;
        int end = e + start + MINL - 1;
        out[b]      = s;
        out[16 + b] = (float)start;
        out[32 + b] = (float)end;
        out[48 + b] = any ? 1.0f : 0.0f;
        out[64 + b] = (float)vc;
    }
}

// ---------------------------------------------------------------------------
extern "C" void kernel_launch(void* const* d_in, const int* in_sizes, int n_in,
                              void* d_out, int out_size, void* d_ws, size_t ws_size,
                              hipStream_t stream) {
    const float* x       = (const float*)d_in[0];   // [16][64][60]
    const float* uf      = (const float*)d_in[1];   // [600][60]
    const float* W       = (const float*)d_in[2];   // [60][256]
    const int*   lengths = (const int*)d_in[3];     // [16]
    const int*   seg     = (const int*)d_in[4];     // [10000][10]
    const int*   vlen    = (const int*)d_in[5];     // [10000]
    float* out = (float*)d_out;
    float* ws  = (float*)d_ws;

    float*        unT = ws + UNT_OFF;
    float*        wnT = ws + WNT_OFF;
    float*        sim = ws + SIM_OFF;
    unsigned int* cnt = (unsigned int*)(ws + CNT_OFF);
    unsigned int* srt = (unsigned int*)(ws + SRT_OFF);
    float*        val = ws + VAL_OFF;
    int*          voc = (int*)(ws + VOC_OFF);

    hipMemsetAsync(cnt, 0, 8 * sizeof(unsigned int), stream);  // bucket cursors
    k_prep<<<446, 256, 0, stream>>>(seg, vlen, x, uf, W, cnt, srt, unT, wnT);
    k_sim<<<512, 320, 0, stream>>>(unT, wnT, sim);
    k_score<<<1024, 512, 0, stream>>>(sim, srt, cnt, lengths, val, voc);
    k_final<<<BB, 512, 0, stream>>>(val, voc, out);
}

// Round 7
// 145.947 us; speedup vs baseline: 1.1886x; 1.1886x over previous
//
#include <hip/hip_runtime.h>
#include <math.h>

// Problem constants (from reference setup_inputs)
#define BB 16
#define LL 64
#define FF 60
#define DD 256
#define UU 600
#define VV 10000
#define JMAX 10
#define MINL 4
#define EE 7           // MAX_LEN - MIN_LEN + 1
#define NEG (-1e9f)
#define TH 0.05f
#define BCAP 10240     // per-bucket record capacity (>= V)

// Workspace layout in u32/float units (ws_size ~256 MB per harness fill — ample).
#define UNT_OFF   0                         // unT[256][640]  (u padded 600->640)
#define WNT_OFF   163840                    // wnT[256][1024] (bl = b*64+l)
#define SIM_OFF   425984                    // sim[16][64][600]
#define CNT_OFF   1040384                   // uint cnt[8] (memset to 0)
#define SRT_OFF   1040392                   // records: 7 buckets x 10240 x 8 u32 (32B-aligned)
#define VAL_OFF   1613832                   // val[2][16][64][7]  (per v-half)
#define VOC_OFF   1628168                   // int voc[2][16][64][7]

// ---------------------------------------------------------------------------
// Fused prep: blocks [0,40) bucket-sort vocab records; blocks [40,446) embed.
// Record (32B): w0..w4 = 10 x u16 LDS indices (u*11+j), w5 = v, w6,w7 pad.
// Bucket e = vlen-4. WAVE-AGGREGATED atomics: one atomicAdd per (wave,bucket)
// via ballot (round-6 bug: 10k per-lane same-address atomics serialized in
// TCC -> 46 us). Order within a wave is lane order; cross-wave order is
// non-deterministic — k_score's update is v-tie-aware so this is safe.
__global__ __launch_bounds__(256) void k_prep(const int* __restrict__ seg,
                                              const int* __restrict__ vlen,
                                              const float* __restrict__ x,
                                              const float* __restrict__ uf,
                                              const float* __restrict__ W,
                                              unsigned int* __restrict__ cnt,
                                              unsigned int* __restrict__ srt,
                                              float* __restrict__ unT,
                                              float* __restrict__ wnT) {
    int blk = blockIdx.x;
    if (blk < 40) {
        int v = blk * 256 + threadIdx.x;
        if (v >= VV) return;
        int lane = threadIdx.x & 63;
        unsigned long long below = (lane == 0) ? 0ull : (~0ull >> (64 - lane));
        const int* s = seg + v * JMAX;
        unsigned int t[10];
#pragma unroll
        for (int j = 0; j < JMAX; ++j) t[j] = (unsigned int)(s[j] * 11 + j);
        int e = vlen[v] - MINL;                       // 0..6
        unsigned int pos = 0;
#pragma unroll
        for (int b2 = 0; b2 < EE; ++b2) {
            unsigned long long m = __ballot(e == b2);
            if (e == b2) {
                int leader = __ffsll((long long)m) - 1;
                unsigned int wc = (unsigned int)__popcll(m);
                unsigned int base = 0;
                if (lane == leader) base = atomicAdd(&cnt[b2], wc);
                base = __shfl(base, leader, 64);
                pos = base + (unsigned int)__popcll(m & below);
            }
        }
        unsigned int* dst = srt + ((size_t)e * BCAP + pos) * 8;
        uint4 qa, qb;
        qa.x = t[0] | (t[1] << 16);
        qa.y = t[2] | (t[3] << 16);
        qa.z = t[4] | (t[5] << 16);
        qa.w = t[6] | (t[7] << 16);
        qb.x = t[8] | (t[9] << 16);
        qb.y = (unsigned int)v;
        qb.z = 0; qb.w = 0;
        ((uint4*)dst)[0] = qa;
        ((uint4*)dst)[1] = qb;
    } else {
        // embed: wave w of block handles row (blk-40)*4 + w; 1624 rows total.
        int w = threadIdx.x >> 6;
        int lane = threadIdx.x & 63;
        int id = (blk - 40) * 4 + w;
        const float* row;
        float* outB;
        int stride, col;
        if (id < UU) { row = uf + id * FF; outB = unT; stride = 640;  col = id; }
        else { int bl = id - UU; row = x + bl * FF; outB = wnT; stride = 1024; col = bl; }

        float r0 = 0.f, r1 = 0.f, r2 = 0.f, r3 = 0.f;
#pragma unroll 4
        for (int f = 0; f < FF; ++f) {
            float xv = row[f];  // wave-uniform broadcast load
            r0 += xv * W[f * DD + lane];
            r1 += xv * W[f * DD + lane + 64];
            r2 += xv * W[f * DD + lane + 128];
            r3 += xv * W[f * DD + lane + 192];
        }
        float ss = r0 * r0 + r1 * r1 + r2 * r2 + r3 * r3;
#pragma unroll
        for (int m = 32; m > 0; m >>= 1) ss += __shfl_xor(ss, m, 64);
        float inv = 1.0f / (sqrtf(ss) + 1e-8f);   // matches ref x/(norm+1e-8)
        outB[(lane      ) * stride + col] = r0 * inv;
        outB[(lane +  64) * stride + col] = r1 * inv;
        outB[(lane + 128) * stride + col] = r2 * inv;
        outB[(lane + 192) * stride + col] = r3 * inv;
    }
}

// ---------------------------------------------------------------------------
// sim[b][l][u] = wn[bl] . un[u].  512 blocks = (b, l-quad, u-half), 320
// threads. Thread tile: 4l x 1u; wn read as wave-uniform float4 per d.
__global__ __launch_bounds__(320) void k_sim(const float* __restrict__ unT,
                                             const float* __restrict__ wnT,
                                             float* __restrict__ sim) {
    int blk = blockIdx.x;
    int b  = blk >> 5;
    int r  = blk & 31;
    int l0 = (r >> 1) * 4;
    int uh = r & 1;
    int bl0 = b * 64 + l0;
    int u = uh * 320 + threadIdx.x;     // < 640 (unT padded; stores guarded)

    float a0 = 0.f, a1 = 0.f, a2 = 0.f, a3 = 0.f;
#pragma unroll 8
    for (int d = 0; d < DD; ++d) {
        float4 wv = *(const float4*)(wnT + d * 1024 + bl0);  // uniform 16B
        float v  = unT[d * 640 + u];
        a0 += wv.x * v;
        a1 += wv.y * v;
        a2 += wv.z * v;
        a3 += wv.w * v;
    }
    if (u < UU) {
        sim[(bl0 + 0) * UU + u] = a0;
        sim[(bl0 + 1) * UU + u] = a1;
        sim[(bl0 + 2) * UU + u] = a2;
        sim[(bl0 + 3) * UU + u] = a3;
    }
}

// ---------------------------------------------------------------------------
// Per-bucket pass with STATIC k: exactly K ds_read2-pairs per record, one
// tie-aware best update (handles unstable bucket order: equal score -> lower
// v wins, matching jnp.argmax first-index semantics).
template<int K>
__device__ __forceinline__ void bucket_pass(const unsigned int* __restrict__ srt,
                                            const float* __restrict__ lds,
                                            int e, int half, int n, int tid,
                                            float& s0, int& w0,
                                            float& s1, int& w1) {
    int n0 = n >> 1;
    int lo = half ? n0 : 0;
    int hi = half ? n : n0;
    for (int p = lo + tid; p < hi; p += 512) {
        const uint4* pp = (const uint4*)(srt + ((size_t)e * BCAP + p) * 8);
        uint4 qa = pp[0];
        uint4 qb = pp[1];
        unsigned int tw[5] = {qa.x, qa.y, qa.z, qa.w, qb.x};
        int v = (int)qb.y;
        float a0 = 0.f, a1 = 0.f;
#pragma unroll
        for (int j = 0; j < K; ++j) {
            int idx = (int)((tw[j >> 1] >> ((j & 1) * 16)) & 0xffffu);
            float x0 = lds[idx];
            float x1 = lds[idx + 1];
            a0 += x0;
            a1 += x1;
        }
        bool p0 = (a0 > s0) || (a0 == s0 && v < w0);
        bool p1 = (a1 > s1) || (a1 == s1 && v < w1);
        s0 = p0 ? a0 : s0;  w0 = p0 ? v : w0;
        s1 = p1 ? a1 : s1;  w1 = p1 ? v : w1;
    }
}

// ---------------------------------------------------------------------------
// Phase 3: 1024 blocks = (v-half, b, l-pair), 512 threads. Stage sim rows
// l0..l0+10 in LDS transposed [u][11] (stride 11, coprime with 32 banks).
// Then 7 static-k bucket passes over sorted records; raw-sum compares,
// normalize winner once at the end.
__global__ __launch_bounds__(512, 8) void k_score(const float* __restrict__ sim,
                                                  const unsigned int* __restrict__ srt,
                                                  const unsigned int* __restrict__ cnt,
                                                  const int* __restrict__ lengths,
                                                  float* __restrict__ val,
                                                  int* __restrict__ voc) {
    __shared__ float lds[UU * 11];   // 26.4 KB
    __shared__ float redS[14][8];    // e*2+dl in [0,14) x 8 waves
    __shared__ int   redV[14][8];

    int blk = blockIdx.x;
    int half = blk >> 9;
    int rest = blk & 511;
    int b  = rest >> 5;
    int l0 = (rest & 31) * 2;
    int tid = threadIdx.x;

    // Stage sim tile -> LDS transposed; rows >= L are the zero-pad region.
    for (int u = tid; u < UU; u += 512) {
#pragma unroll
        for (int r = 0; r < 11; ++r) {
            int m = l0 + r;
            lds[u * 11 + r] = (m < LL) ? sim[(b * 64 + m) * UU + u] : 0.0f;
        }
    }
    __syncthreads();

    int ne[EE];
#pragma unroll
    for (int e = 0; e < EE; ++e) ne[e] = (int)cnt[e];   // uniform, L2-cached

    float bS[EE][2];
    int   bV[EE][2];
#pragma unroll
    for (int e = 0; e < EE; ++e) {
        bS[e][0] = -1e30f; bS[e][1] = -1e30f;
        bV[e][0] = VV;     bV[e][1] = VV;
    }

    bucket_pass<4> (srt, lds, 0, half, ne[0], tid, bS[0][0], bV[0][0], bS[0][1], bV[0][1]);
    bucket_pass<5> (srt, lds, 1, half, ne[1], tid, bS[1][0], bV[1][0], bS[1][1], bV[1][1]);
    bucket_pass<6> (srt, lds, 2, half, ne[2], tid, bS[2][0], bV[2][0], bS[2][1], bV[2][1]);
    bucket_pass<7> (srt, lds, 3, half, ne[3], tid, bS[3][0], bV[3][0], bS[3][1], bV[3][1]);
    bucket_pass<8> (srt, lds, 4, half, ne[4], tid, bS[4][0], bV[4][0], bS[4][1], bV[4][1]);
    bucket_pass<9> (srt, lds, 5, half, ne[5], tid, bS[5][0], bV[5][0], bS[5][1], bV[5][1]);
    bucket_pass<10>(srt, lds, 6, half, ne[6], tid, bS[6][0], bV[6][0], bS[6][1], bV[6][1]);

    int w = tid >> 6, lane = tid & 63;
#pragma unroll
    for (int e = 0; e < EE; ++e) {
#pragma unroll
        for (int dl = 0; dl < 2; ++dl) {
            float s = bS[e][dl];
            int vv = bV[e][dl];
#pragma unroll
            for (int off = 32; off > 0; off >>= 1) {
                float os = __shfl_down(s, off, 64);
                int   ov = __shfl_down(vv, off, 64);
                if (os > s || (os == s && ov < vv)) { s = os; vv = ov; }
            }
            if (lane == 0) { redS[e * 2 + dl][w] = s; redV[e * 2 + dl][w] = vv; }
        }
    }
    __syncthreads();

    if (tid < 14) {   // only indices 0..13 of redS/redV are valid
        int e  = tid >> 1;
        int dl = tid & 1;
        float s = redS[tid][0];
        int  vv = redV[tid][0];
#pragma unroll
        for (int w2 = 1; w2 < 8; ++w2) {
            float os = redS[tid][w2];
            int   ov = redV[tid][w2];
            if (os > s || (os == s && ov < vv)) { s = os; vv = ov; }
        }
        int lg = l0 + dl;
        int k = e + MINL;
        bool viable = (lg + k - 1) < lengths[b];
        float sn = s / (float)k;   // normalize winner only (bit-same as ref a/k)
        int o = (half * BB * LL + b * 64 + lg) * EE + e;
        val[o] = viable ? sn : NEG;
        voc[o] = viable ? vv : 0;  // ref argmax of all-NEG = 0
    }
}

// ---------------------------------------------------------------------------
// Per-b: merge the two v-halves slot-wise (tie -> smaller voc = smaller v),
// then flat argmax over the 448 (l,e) slots (min flat index on ties),
// any_matched = merged max > THRESH. Outputs written as float32 values.
__global__ __launch_bounds__(512) void k_final(const float* __restrict__ val,
                                               const int* __restrict__ voc,
                                               float* __restrict__ out) {
    __shared__ float sS[8];
    __shared__ int   sI[8];
    __shared__ int   sV[8];
    __shared__ int   sA[8];
    int b = blockIdx.x;
    int t = threadIdx.x;
    float s = -3e38f;
    int idx = 1 << 30;
    int vc = 0;
    int any = 0;
    if (t < LL * EE) {
        int o0 = b * LL * EE + t;
        int o1 = BB * LL * EE + o0;
        float s0 = val[o0], s1 = val[o1];
        int   v0 = voc[o0], v1 = voc[o1];
        bool sel = (s1 > s0) || (s1 == s0 && v1 < v0);
        s  = sel ? s1 : s0;
        vc = sel ? v1 : v0;
        idx = t;
        any = (s > TH) ? 1 : 0;
    }
#pragma unroll
    for (int off = 32; off > 0; off >>= 1) {
        float os = __shfl_down(s, off, 64);
        int   oi = __shfl_down(idx, off, 64);
        int   ov = __shfl_down(vc, off, 64);
        int   oa = __shfl_down(any, off, 64);
        if (os > s || (os == s && oi < idx)) { s = os; idx = oi; vc = ov; }
        any |= oa;
    }
    int w = t >> 6, lane = t & 63;
    if (lane == 0) { sS[w] = s; sI[w] = idx; sV[w] = vc; sA[w] = any; }
    __syncthreads();
    if (t == 0) {
        for (int w2 = 1; w2 < 8; ++w2) {
            float os = sS[w2];
            int   oi = sI[w2];
            if (os > s || (os == s && oi < idx)) { s = os; idx = oi; vc = sV[w2]; }
            any |= sA[w2];
        }
        int start = idx / EE;
        int e = idx - start * EE;
        int end = e + start + MINL - 1;
        out[b]      = s;
        out[16 + b] = (float)start;
        out[32 + b] = (float)end;
        out[48 + b] = any ? 1.0f : 0.0f;
        out[64 + b] = (float)vc;
    }
}

// ---------------------------------------------------------------------------
extern "C" void kernel_launch(void* const* d_in, const int* in_sizes, int n_in,
                              void* d_out, int out_size, void* d_ws, size_t ws_size,
                              hipStream_t stream) {
    const float* x       = (const float*)d_in[0];   // [16][64][60]
    const float* uf      = (const float*)d_in[1];   // [600][60]
    const float* W       = (const float*)d_in[2];   // [60][256]
    const int*   lengths = (const int*)d_in[3];     // [16]
    const int*   seg     = (const int*)d_in[4];     // [10000][10]
    const int*   vlen    = (const int*)d_in[5];     // [10000]
    float* out = (float*)d_out;
    float* ws  = (float*)d_ws;

    float*        unT = ws + UNT_OFF;
    float*        wnT = ws + WNT_OFF;
    float*        sim = ws + SIM_OFF;
    unsigned int* cnt = (unsigned int*)(ws + CNT_OFF);
    unsigned int* srt = (unsigned int*)(ws + SRT_OFF);
    float*        val = ws + VAL_OFF;
    int*          voc = (int*)(ws + VOC_OFF);

    hipMemsetAsync(cnt, 0, 8 * sizeof(unsigned int), stream);  // bucket cursors
    k_prep<<<446, 256, 0, stream>>>(seg, vlen, x, uf, W, cnt, srt, unT, wnT);
    k_sim<<<512, 320, 0, stream>>>(unT, wnT, sim);
    k_score<<<1024, 512, 0, stream>>>(sim, srt, cnt, lengths, val, voc);
    k_final<<<BB, 512, 0, stream>>>(val, voc, out);
}

// Round 8
// 132.832 us; speedup vs baseline: 1.3059x; 1.0987x over previous
//
#include <hip/hip_runtime.h>
#include <math.h>

// Problem constants (from reference setup_inputs)
#define BB 16
#define LL 64
#define FF 60
#define DD 256
#define UU 600
#define VV 10000
#define JMAX 10
#define MINL 4
#define EE 7           // MAX_LEN - MIN_LEN + 1
#define NEG (-1e9f)
#define TH 0.05f
#define BCAP 10240     // per-bucket record capacity (>= V)

// Workspace layout in u32/float units (ws_size ~256 MB per harness fill — ample).
#define UNT_OFF   0                         // unT[256][640]  (u padded 600->640)
#define WNT_OFF   163840                    // wnT[256][1024] (bl = b*64+l)
#define SIM_OFF   425984                    // sim[16][64][600]
#define CNT_OFF   1040384                   // uint cnt[8] (memset to 0)
#define SRT_OFF   1040392                   // records: 7 buckets x 10240 x 8 u32 (32B-aligned)
#define VAL_OFF   1613832                   // val[2][16][64][7]  (per v-half)
#define VOC_OFF   1628168                   // int voc[2][16][64][7]

// ---------------------------------------------------------------------------
// Fused prep: blocks [0,40) bucket-sort vocab records; blocks [40,446) embed.
// Record (32B): w0..w4 = 10 x u16 LDS indices (u*11+j), w5 = v, w6,w7 pad.
// Bucket e = vlen-4. Wave-aggregated atomics (one atomicAdd per wave-bucket).
__global__ __launch_bounds__(256) void k_prep(const int* __restrict__ seg,
                                              const int* __restrict__ vlen,
                                              const float* __restrict__ x,
                                              const float* __restrict__ uf,
                                              const float* __restrict__ W,
                                              unsigned int* __restrict__ cnt,
                                              unsigned int* __restrict__ srt,
                                              float* __restrict__ unT,
                                              float* __restrict__ wnT) {
    int blk = blockIdx.x;
    if (blk < 40) {
        int v = blk * 256 + threadIdx.x;
        if (v >= VV) return;
        int lane = threadIdx.x & 63;
        unsigned long long below = (lane == 0) ? 0ull : (~0ull >> (64 - lane));
        const int* s = seg + v * JMAX;
        unsigned int t[10];
#pragma unroll
        for (int j = 0; j < JMAX; ++j) t[j] = (unsigned int)(s[j] * 11 + j);
        int e = vlen[v] - MINL;                       // 0..6
        unsigned int pos = 0;
#pragma unroll
        for (int b2 = 0; b2 < EE; ++b2) {
            unsigned long long m = __ballot(e == b2);
            if (e == b2) {
                int leader = __ffsll((long long)m) - 1;
                unsigned int wc = (unsigned int)__popcll(m);
                unsigned int base = 0;
                if (lane == leader) base = atomicAdd(&cnt[b2], wc);
                base = __shfl(base, leader, 64);
                pos = base + (unsigned int)__popcll(m & below);
            }
        }
        unsigned int* dst = srt + ((size_t)e * BCAP + pos) * 8;
        uint4 qa, qb;
        qa.x = t[0] | (t[1] << 16);
        qa.y = t[2] | (t[3] << 16);
        qa.z = t[4] | (t[5] << 16);
        qa.w = t[6] | (t[7] << 16);
        qb.x = t[8] | (t[9] << 16);
        qb.y = (unsigned int)v;
        qb.z = 0; qb.w = 0;
        ((uint4*)dst)[0] = qa;
        ((uint4*)dst)[1] = qb;
    } else {
        // embed: wave w of block handles row (blk-40)*4 + w; 1624 rows total.
        int w = threadIdx.x >> 6;
        int lane = threadIdx.x & 63;
        int id = (blk - 40) * 4 + w;
        const float* row;
        float* outB;
        int stride, col;
        if (id < UU) { row = uf + id * FF; outB = unT; stride = 640;  col = id; }
        else { int bl = id - UU; row = x + bl * FF; outB = wnT; stride = 1024; col = bl; }

        float r0 = 0.f, r1 = 0.f, r2 = 0.f, r3 = 0.f;
#pragma unroll 4
        for (int f = 0; f < FF; ++f) {
            float xv = row[f];  // wave-uniform broadcast load
            r0 += xv * W[f * DD + lane];
            r1 += xv * W[f * DD + lane + 64];
            r2 += xv * W[f * DD + lane + 128];
            r3 += xv * W[f * DD + lane + 192];
        }
        float ss = r0 * r0 + r1 * r1 + r2 * r2 + r3 * r3;
#pragma unroll
        for (int m = 32; m > 0; m >>= 1) ss += __shfl_xor(ss, m, 64);
        float inv = 1.0f / (sqrtf(ss) + 1e-8f);   // matches ref x/(norm+1e-8)
        outB[(lane      ) * stride + col] = r0 * inv;
        outB[(lane +  64) * stride + col] = r1 * inv;
        outB[(lane + 128) * stride + col] = r2 * inv;
        outB[(lane + 192) * stride + col] = r3 * inv;
    }
}

// ---------------------------------------------------------------------------
// sim[b][l][u] = wn[bl] . un[u].  512 blocks = (b, l-quad, u-half), 320
// threads. Thread tile: 4l x 1u; wn read as wave-uniform float4 per d.
__global__ __launch_bounds__(320) void k_sim(const float* __restrict__ unT,
                                             const float* __restrict__ wnT,
                                             float* __restrict__ sim) {
    int blk = blockIdx.x;
    int b  = blk >> 5;
    int r  = blk & 31;
    int l0 = (r >> 1) * 4;
    int uh = r & 1;
    int bl0 = b * 64 + l0;
    int u = uh * 320 + threadIdx.x;     // < 640 (unT padded; stores guarded)

    float a0 = 0.f, a1 = 0.f, a2 = 0.f, a3 = 0.f;
#pragma unroll 8
    for (int d = 0; d < DD; ++d) {
        float4 wv = *(const float4*)(wnT + d * 1024 + bl0);  // uniform 16B
        float v  = unT[d * 640 + u];
        a0 += wv.x * v;
        a1 += wv.y * v;
        a2 += wv.z * v;
        a3 += wv.w * v;
    }
    if (u < UU) {
        sim[(bl0 + 0) * UU + u] = a0;
        sim[(bl0 + 1) * UU + u] = a1;
        sim[(bl0 + 2) * UU + u] = a2;
        sim[(bl0 + 3) * UU + u] = a3;
    }
}

// ---------------------------------------------------------------------------
// Per-wave segment pass, STATIC K: wave's lanes stride records [r0, r1) of
// bucket e; K ds_read2-pairs per record; tie-aware update (lower v wins on
// equal score = jnp first-index semantics, robust to unsorted buckets).
// Ends with wave shuffle-reduce and a single write to this wave's red slot.
template<int K>
__device__ __forceinline__ void seg_pass(const unsigned int* __restrict__ srt,
                                         const float* __restrict__ lds,
                                         int e, int r0, int r1, int lane, int wave,
                                         float (*redS)[8], int (*redV)[8]) {
    float s0 = -1e30f, s1 = -1e30f;
    int w0 = VV, w1 = VV;
    for (int p = r0 + lane; p < r1; p += 64) {
        const uint4* pp = (const uint4*)(srt + ((size_t)e * BCAP + p) * 8);
        uint4 qa = pp[0];
        uint4 qb = pp[1];
        unsigned int tw[5] = {qa.x, qa.y, qa.z, qa.w, qb.x};
        int v = (int)qb.y;
        float a0 = 0.f, a1 = 0.f;
#pragma unroll
        for (int j = 0; j < K; ++j) {
            int idx = (int)((tw[j >> 1] >> ((j & 1) * 16)) & 0xffffu);
            a0 += lds[idx];
            a1 += lds[idx + 1];
        }
        bool p0 = (a0 > s0) || (a0 == s0 && v < w0);
        bool p1 = (a1 > s1) || (a1 == s1 && v < w1);
        s0 = p0 ? a0 : s0;  w0 = p0 ? v : w0;
        s1 = p1 ? a1 : s1;  w1 = p1 ? v : w1;
    }
#pragma unroll
    for (int off = 32; off > 0; off >>= 1) {
        float os0 = __shfl_down(s0, off, 64);
        int   ov0 = __shfl_down(w0, off, 64);
        float os1 = __shfl_down(s1, off, 64);
        int   ov1 = __shfl_down(w1, off, 64);
        if (os0 > s0 || (os0 == s0 && ov0 < w0)) { s0 = os0; w0 = ov0; }
        if (os1 > s1 || (os1 == s1 && ov1 < w1)) { s1 = os1; w1 = ov1; }
    }
    if (lane == 0) {
        redS[e * 2 + 0][wave] = s0; redV[e * 2 + 0][wave] = w0;
        redS[e * 2 + 1][wave] = s1; redV[e * 2 + 1][wave] = w1;
    }
}

// ---------------------------------------------------------------------------
// Phase 3: 1024 blocks = (v-half, b, l-pair), 512 threads. Stage sim rows
// l0..l0+10 in LDS transposed [u][11]. Then each WAVE takes a
// work-proportional contiguous slice of the bucket-sorted record space
// (quota = sum(n_e*K_e)/8) -> ONE deep static-K loop per touched bucket
// (round-7 fix: 7 shallow passes of ~1.4 iter were all ramp latency).
__global__ __launch_bounds__(512, 8) void k_score(const float* __restrict__ sim,
                                                  const unsigned int* __restrict__ srt,
                                                  const unsigned int* __restrict__ cnt,
                                                  const int* __restrict__ lengths,
                                                  float* __restrict__ val,
                                                  int* __restrict__ voc) {
    __shared__ float lds[UU * 11];   // 26.4 KB
    __shared__ float redS[14][8];    // [e*2+dl][wave]
    __shared__ int   redV[14][8];

    int blk = blockIdx.x;
    int half = blk >> 9;
    int rest = blk & 511;
    int b  = rest >> 5;
    int l0 = (rest & 31) * 2;
    int tid = threadIdx.x;

    if (tid < 112) {                 // init all reduction slots
        redS[tid >> 3][tid & 7] = -1e30f;
        redV[tid >> 3][tid & 7] = VV;
    }
    // Stage sim tile -> LDS transposed; rows >= L are the zero-pad region.
    for (int u = tid; u < UU; u += 512) {
#pragma unroll
        for (int r = 0; r < 11; ++r) {
            int m = l0 + r;
            lds[u * 11 + r] = (m < LL) ? sim[(b * 64 + m) * UU + u] : 0.0f;
        }
    }
    __syncthreads();

    int wave = tid >> 6, lane = tid & 63;

    // Work-proportional wave slicing over this half's records.
    unsigned nlo[EE], nhi[EE], Bw[EE];
    unsigned Wtot = 0;
#pragma unroll
    for (int e = 0; e < EE; ++e) {
        unsigned n = cnt[e];
        unsigned lo = half ? (n >> 1) : 0;
        unsigned hi = half ? n : (n >> 1);
        nlo[e] = lo; nhi[e] = hi;
        Bw[e] = Wtot;
        Wtot += (hi - lo) * (unsigned)(e + MINL);
    }
    unsigned qlo = (unsigned)(((unsigned long long)Wtot * (unsigned)wave) >> 3);
    unsigned qhi = (unsigned)(((unsigned long long)Wtot * (unsigned)(wave + 1)) >> 3);

#pragma unroll
    for (int e = 0; e < EE; ++e) {
        unsigned K = (unsigned)(e + MINL);
        unsigned segw = (nhi[e] - nlo[e]) * K;
        unsigned Be = Bw[e];
        if (qhi <= Be || qlo >= Be + segw || segw == 0) continue;
        unsigned a = (qlo > Be) ? (qlo - Be) : 0;
        unsigned bb = qhi - Be; if (bb > segw) bb = segw;
        int r0 = (int)(nlo[e] + (a + K - 1) / K);
        int r1 = (int)(nlo[e] + (bb + K - 1) / K);
        if (r1 <= r0) continue;
        switch (e) {   // wave-uniform branch
            case 0: seg_pass<4> (srt, lds, 0, r0, r1, lane, wave, redS, redV); break;
            case 1: seg_pass<5> (srt, lds, 1, r0, r1, lane, wave, redS, redV); break;
            case 2: seg_pass<6> (srt, lds, 2, r0, r1, lane, wave, redS, redV); break;
            case 3: seg_pass<7> (srt, lds, 3, r0, r1, lane, wave, redS, redV); break;
            case 4: seg_pass<8> (srt, lds, 4, r0, r1, lane, wave, redS, redV); break;
            case 5: seg_pass<9> (srt, lds, 5, r0, r1, lane, wave, redS, redV); break;
            case 6: seg_pass<10>(srt, lds, 6, r0, r1, lane, wave, redS, redV); break;
        }
    }
    __syncthreads();

    if (tid < 14) {   // reduce 8 wave-slots per (e, dl)
        int e  = tid >> 1;
        int dl = tid & 1;
        float s = redS[tid][0];
        int  vv = redV[tid][0];
#pragma unroll
        for (int w2 = 1; w2 < 8; ++w2) {
            float os = redS[tid][w2];
            int   ov = redV[tid][w2];
            if (os > s || (os == s && ov < vv)) { s = os; vv = ov; }
        }
        int lg = l0 + dl;
        int k = e + MINL;
        bool viable = (lg + k - 1) < lengths[b];
        float sn = s / (float)k;   // normalize winner only (bit-same as ref a/k)
        int o = (half * BB * LL + b * 64 + lg) * EE + e;
        val[o] = viable ? sn : NEG;
        voc[o] = viable ? vv : 0;  // ref argmax of all-NEG = 0
    }
}

// ---------------------------------------------------------------------------
// Per-b: merge the two v-halves slot-wise (tie -> smaller voc = smaller v),
// then flat argmax over the 448 (l,e) slots (min flat index on ties),
// any_matched = merged max > THRESH. Outputs written as float32 values.
__global__ __launch_bounds__(512) void k_final(const float* __restrict__ val,
                                               const int* __restrict__ voc,
                                               float* __restrict__ out) {
    __shared__ float sS[8];
    __shared__ int   sI[8];
    __shared__ int   sV[8];
    __shared__ int   sA[8];
    int b = blockIdx.x;
    int t = threadIdx.x;
    float s = -3e38f;
    int idx = 1 << 30;
    int vc = 0;
    int any = 0;
    if (t < LL * EE) {
        int o0 = b * LL * EE + t;
        int o1 = BB * LL * EE + o0;
        float s0 = val[o0], s1 = val[o1];
        int   v0 = voc[o0], v1 = voc[o1];
        bool sel = (s1 > s0) || (s1 == s0 && v1 < v0);
        s  = sel ? s1 : s0;
        vc = sel ? v1 : v0;
        idx = t;
        any = (s > TH) ? 1 : 0;
    }
#pragma unroll
    for (int off = 32; off > 0; off >>= 1) {
        float os = __shfl_down(s, off, 64);
        int   oi = __shfl_down(idx, off, 64);
        int   ov = __shfl_down(vc, off, 64);
        int   oa = __shfl_down(any, off, 64);
        if (os > s || (os == s && oi < idx)) { s = os; idx = oi; vc = ov; }
        any |= oa;
    }
    int w = t >> 6, lane = t & 63;
    if (lane == 0) { sS[w] = s; sI[w] = idx; sV[w] = vc; sA[w] = any; }
    __syncthreads();
    if (t == 0) {
        for (int w2 = 1; w2 < 8; ++w2) {
            float os = sS[w2];
            int   oi = sI[w2];
            if (os > s || (os == s && oi < idx)) { s = os; idx = oi; vc = sV[w2]; }
            any |= sA[w2];
        }
        int start = idx / EE;
        int e = idx - start * EE;
        int end = e + start + MINL - 1;
        out[b]      = s;
        out[16 + b] = (float)start;
        out[32 + b] = (float)end;
        out[48 + b] = any ? 1.0f : 0.0f;
        out[64 + b] = (float)vc;
    }
}

// ---------------------------------------------------------------------------
extern "C" void kernel_launch(void* const* d_in, const int* in_sizes, int n_in,
                              void* d_out, int out_size, void* d_ws, size_t ws_size,
                              hipStream_t stream) {
    const float* x       = (const float*)d_in[0];   // [16][64][60]
    const float* uf      = (const float*)d_in[1];   // [600][60]
    const float* W       = (const float*)d_in[2];   // [60][256]
    const int*   lengths = (const int*)d_in[3];     // [16]
    const int*   seg     = (const int*)d_in[4];     // [10000][10]
    const int*   vlen    = (const int*)d_in[5];     // [10000]
    float* out = (float*)d_out;
    float* ws  = (float*)d_ws;

    float*        unT = ws + UNT_OFF;
    float*        wnT = ws + WNT_OFF;
    float*        sim = ws + SIM_OFF;
    unsigned int* cnt = (unsigned int*)(ws + CNT_OFF);
    unsigned int* srt = (unsigned int*)(ws + SRT_OFF);
    float*        val = ws + VAL_OFF;
    int*          voc = (int*)(ws + VOC_OFF);

    hipMemsetAsync(cnt, 0, 8 * sizeof(unsigned int), stream);  // bucket cursors
    k_prep<<<446, 256, 0, stream>>>(seg, vlen, x, uf, W, cnt, srt, unT, wnT);
    k_sim<<<512, 320, 0, stream>>>(unT, wnT, sim);
    k_score<<<1024, 512, 0, stream>>>(sim, srt, cnt, lengths, val, voc);
    k_final<<<BB, 512, 0, stream>>>(val, voc, out);
}

// Round 9
// 131.376 us; speedup vs baseline: 1.3204x; 1.0111x over previous
//
#include <hip/hip_runtime.h>
#include <math.h>

// Problem constants (from reference setup_inputs)
#define BB 16
#define LL 64
#define FF 60
#define DD 256
#define UU 600
#define VV 10000
#define JMAX 10
#define MINL 4
#define EE 7           // MAX_LEN - MIN_LEN + 1
#define NEG (-1e9f)
#define TH 0.05f
#define BCAP 10240     // per-bucket record capacity (>= V)

// Workspace layout in u32/float units (ws_size ~256 MB per harness fill — ample).
#define UNT_OFF   0                         // unT[256][640]  (u padded 600->640)
#define WNT_OFF   163840                    // wnT[256][1024] (bl = b*64+l)
#define SIM_OFF   425984                    // sim[16][64][600]
#define CNT_OFF   1040384                   // uint cnt[8] (memset to 0)
#define SRT_OFF   1040392                   // records: 7 buckets x 10240 x 8 u32 (32B-aligned)
#define VAL_OFF   1613832                   // val[2][16][64][7]  (per v-half)
#define VOC_OFF   1628168                   // int voc[2][16][64][7]

// ---------------------------------------------------------------------------
// Fused prep: blocks [0,40) bucket-sort vocab records; blocks [40,446) embed.
// Record (32B): w0..w4 = 10 x u16 LDS indices (u*13+j), w5 = v, w6,w7 pad.
// Bucket e = vlen-4. Wave-aggregated atomics (one atomicAdd per wave-bucket).
__global__ __launch_bounds__(256) void k_prep(const int* __restrict__ seg,
                                              const int* __restrict__ vlen,
                                              const float* __restrict__ x,
                                              const float* __restrict__ uf,
                                              const float* __restrict__ W,
                                              unsigned int* __restrict__ cnt,
                                              unsigned int* __restrict__ srt,
                                              float* __restrict__ unT,
                                              float* __restrict__ wnT) {
    int blk = blockIdx.x;
    if (blk < 40) {
        int v = blk * 256 + threadIdx.x;
        if (v >= VV) return;
        int lane = threadIdx.x & 63;
        unsigned long long below = (lane == 0) ? 0ull : (~0ull >> (64 - lane));
        const int* s = seg + v * JMAX;
        unsigned int t[10];
#pragma unroll
        for (int j = 0; j < JMAX; ++j) t[j] = (unsigned int)(s[j] * 13 + j);
        int e = vlen[v] - MINL;                       // 0..6
        unsigned int pos = 0;
#pragma unroll
        for (int b2 = 0; b2 < EE; ++b2) {
            unsigned long long m = __ballot(e == b2);
            if (e == b2) {
                int leader = __ffsll((long long)m) - 1;
                unsigned int wc = (unsigned int)__popcll(m);
                unsigned int base = 0;
                if (lane == leader) base = atomicAdd(&cnt[b2], wc);
                base = __shfl(base, leader, 64);
                pos = base + (unsigned int)__popcll(m & below);
            }
        }
        unsigned int* dst = srt + ((size_t)e * BCAP + pos) * 8;
        uint4 qa, qb;
        qa.x = t[0] | (t[1] << 16);
        qa.y = t[2] | (t[3] << 16);
        qa.z = t[4] | (t[5] << 16);
        qa.w = t[6] | (t[7] << 16);
        qb.x = t[8] | (t[9] << 16);
        qb.y = (unsigned int)v;
        qb.z = 0; qb.w = 0;
        ((uint4*)dst)[0] = qa;
        ((uint4*)dst)[1] = qb;
    } else {
        // embed: wave w of block handles row (blk-40)*4 + w; 1624 rows total.
        int w = threadIdx.x >> 6;
        int lane = threadIdx.x & 63;
        int id = (blk - 40) * 4 + w;
        const float* row;
        float* outB;
        int stride, col;
        if (id < UU) { row = uf + id * FF; outB = unT; stride = 640;  col = id; }
        else { int bl = id - UU; row = x + bl * FF; outB = wnT; stride = 1024; col = bl; }

        float r0 = 0.f, r1 = 0.f, r2 = 0.f, r3 = 0.f;
#pragma unroll 4
        for (int f = 0; f < FF; ++f) {
            float xv = row[f];  // wave-uniform broadcast load
            r0 += xv * W[f * DD + lane];
            r1 += xv * W[f * DD + lane + 64];
            r2 += xv * W[f * DD + lane + 128];
            r3 += xv * W[f * DD + lane + 192];
        }
        float ss = r0 * r0 + r1 * r1 + r2 * r2 + r3 * r3;
#pragma unroll
        for (int m = 32; m > 0; m >>= 1) ss += __shfl_xor(ss, m, 64);
        float inv = 1.0f / (sqrtf(ss) + 1e-8f);   // matches ref x/(norm+1e-8)
        outB[(lane      ) * stride + col] = r0 * inv;
        outB[(lane +  64) * stride + col] = r1 * inv;
        outB[(lane + 128) * stride + col] = r2 * inv;
        outB[(lane + 192) * stride + col] = r3 * inv;
    }
}

// ---------------------------------------------------------------------------
// sim[b][l][u] = wn[bl] . un[u].  512 blocks = (b, l-quad, u-half), 320
// threads. Thread tile: 4l x 1u; wn read as wave-uniform float4 per d.
// Early-exit: rows >= lengths[b] are never read by viable spans.
__global__ __launch_bounds__(320) void k_sim(const float* __restrict__ unT,
                                             const float* __restrict__ wnT,
                                             const int* __restrict__ lengths,
                                             float* __restrict__ sim) {
    int blk = blockIdx.x;
    int b  = blk >> 5;
    int r  = blk & 31;
    int l0 = (r >> 1) * 4;
    if (l0 >= lengths[b]) return;       // rows beyond sentence length unused
    int uh = r & 1;
    int bl0 = b * 64 + l0;
    int u = uh * 320 + threadIdx.x;     // < 640 (unT padded; stores guarded)

    float a0 = 0.f, a1 = 0.f, a2 = 0.f, a3 = 0.f;
#pragma unroll 8
    for (int d = 0; d < DD; ++d) {
        float4 wv = *(const float4*)(wnT + d * 1024 + bl0);  // uniform 16B
        float v  = unT[d * 640 + u];
        a0 += wv.x * v;
        a1 += wv.y * v;
        a2 += wv.z * v;
        a3 += wv.w * v;
    }
    if (u < UU) {
        sim[(bl0 + 0) * UU + u] = a0;
        sim[(bl0 + 1) * UU + u] = a1;
        sim[(bl0 + 2) * UU + u] = a2;
        sim[(bl0 + 3) * UU + u] = a3;
    }
}

// ---------------------------------------------------------------------------
// Per-wave segment pass, STATIC K, 4 l-positions per record: K index
// extracts, 2K ds_read2 (idx..idx+3), 4 tie-aware updates (lower v wins on
// equal score = jnp first-index semantics, robust to unsorted buckets).
template<int K>
__device__ __forceinline__ void seg_pass4(const unsigned int* __restrict__ srt,
                                          const float* __restrict__ lds,
                                          int e, int r0, int r1, int lane, int wave,
                                          float (*redS)[8], int (*redV)[8]) {
    float s0 = -1e30f, s1 = -1e30f, s2 = -1e30f, s3 = -1e30f;
    int w0 = VV, w1 = VV, w2 = VV, w3 = VV;
    for (int p = r0 + lane; p < r1; p += 64) {
        const uint4* pp = (const uint4*)(srt + ((size_t)e * BCAP + p) * 8);
        uint4 qa = pp[0];
        uint4 qb = pp[1];
        unsigned int tw[5] = {qa.x, qa.y, qa.z, qa.w, qb.x};
        int v = (int)qb.y;
        float a0 = 0.f, a1 = 0.f, a2 = 0.f, a3 = 0.f;
#pragma unroll
        for (int j = 0; j < K; ++j) {
            int idx = (int)((tw[j >> 1] >> ((j & 1) * 16)) & 0xffffu);
            a0 += lds[idx];
            a1 += lds[idx + 1];
            a2 += lds[idx + 2];
            a3 += lds[idx + 3];
        }
        bool p0 = (a0 > s0) || (a0 == s0 && v < w0);
        bool p1 = (a1 > s1) || (a1 == s1 && v < w1);
        bool p2 = (a2 > s2) || (a2 == s2 && v < w2);
        bool p3 = (a3 > s3) || (a3 == s3 && v < w3);
        s0 = p0 ? a0 : s0;  w0 = p0 ? v : w0;
        s1 = p1 ? a1 : s1;  w1 = p1 ? v : w1;
        s2 = p2 ? a2 : s2;  w2 = p2 ? v : w2;
        s3 = p3 ? a3 : s3;  w3 = p3 ? v : w3;
    }
#pragma unroll
    for (int off = 32; off > 0; off >>= 1) {
        float os; int ov;
        os = __shfl_down(s0, off, 64); ov = __shfl_down(w0, off, 64);
        if (os > s0 || (os == s0 && ov < w0)) { s0 = os; w0 = ov; }
        os = __shfl_down(s1, off, 64); ov = __shfl_down(w1, off, 64);
        if (os > s1 || (os == s1 && ov < w1)) { s1 = os; w1 = ov; }
        os = __shfl_down(s2, off, 64); ov = __shfl_down(w2, off, 64);
        if (os > s2 || (os == s2 && ov < w2)) { s2 = os; w2 = ov; }
        os = __shfl_down(s3, off, 64); ov = __shfl_down(w3, off, 64);
        if (os > s3 || (os == s3 && ov < w3)) { s3 = os; w3 = ov; }
    }
    if (lane == 0) {
        redS[e * 4 + 0][wave] = s0; redV[e * 4 + 0][wave] = w0;
        redS[e * 4 + 1][wave] = s1; redV[e * 4 + 1][wave] = w1;
        redS[e * 4 + 2][wave] = s2; redV[e * 4 + 2][wave] = w2;
        redS[e * 4 + 3][wave] = s3; redV[e * 4 + 3][wave] = w3;
    }
}

// ---------------------------------------------------------------------------
// Phase 3: 512 blocks = (v-half, b, l-QUAD), 512 threads. Stage sim rows
// l0..l0+12 in LDS transposed [u][13] (stride 13, coprime with 32 banks).
// Length-aware: bucket e scanned only if l0+e+3 < len; blocks with no
// active bucket write NEG and exit before staging (~55% work cut).
// Wave-sliced deep loops (work-proportional quota over active buckets).
__global__ __launch_bounds__(512, 8) void k_score(const float* __restrict__ sim,
                                                  const unsigned int* __restrict__ srt,
                                                  const unsigned int* __restrict__ cnt,
                                                  const int* __restrict__ lengths,
                                                  float* __restrict__ val,
                                                  int* __restrict__ voc) {
    __shared__ float lds[UU * 13];   // 31.2 KB
    __shared__ float redS[28][8];    // [e*4+dl][wave]
    __shared__ int   redV[28][8];

    int blk = blockIdx.x;
    int half = blk >> 8;
    int rest = blk & 255;
    int b  = rest >> 4;
    int l0 = (rest & 15) * 4;
    int tid = threadIdx.x;
    int len = lengths[b];            // uniform scalar load

    if (l0 + MINL - 1 >= len) {      // even shortest word at largest... l0 base: no bucket active
        if (tid < 28) {
            int e  = tid >> 2;
            int dl = tid & 3;
            int o = (half * BB * LL + b * 64 + l0 + dl) * EE + e;
            val[o] = NEG;
            voc[o] = 0;
        }
        return;                       // block-uniform: no barrier hazards
    }

    if (tid < 224) {                 // init all 28x8 reduction slots
        redS[tid >> 3][tid & 7] = -1e30f;
        redV[tid >> 3][tid & 7] = VV;
    }
    // Stage sim tile -> LDS transposed; rows >= L are the zero-pad region.
    for (int u = tid; u < UU; u += 512) {
#pragma unroll
        for (int r = 0; r < 13; ++r) {
            int m = l0 + r;
            lds[u * 13 + r] = (m < LL) ? sim[(b * 64 + m) * UU + u] : 0.0f;
        }
    }
    __syncthreads();

    int wave = tid >> 6, lane = tid & 63;

    // Work-proportional wave slicing over this half's ACTIVE buckets.
    unsigned nlo[EE], nhi[EE], Bw[EE];
    unsigned Wtot = 0;
#pragma unroll
    for (int e = 0; e < EE; ++e) {
        unsigned n = cnt[e];
        unsigned lo = half ? (n >> 1) : 0;
        unsigned hi = half ? n : (n >> 1);
        if (l0 + e + MINL - 1 >= len) { lo = 0; hi = 0; }  // bucket dead for whole quad
        nlo[e] = lo; nhi[e] = hi;
        Bw[e] = Wtot;
        Wtot += (hi - lo) * (unsigned)(e + MINL);
    }
    unsigned qlo = (unsigned)(((unsigned long long)Wtot * (unsigned)wave) >> 3);
    unsigned qhi = (unsigned)(((unsigned long long)Wtot * (unsigned)(wave + 1)) >> 3);

#pragma unroll
    for (int e = 0; e < EE; ++e) {
        unsigned K = (unsigned)(e + MINL);
        unsigned segw = (nhi[e] - nlo[e]) * K;
        unsigned Be = Bw[e];
        if (qhi <= Be || qlo >= Be + segw || segw == 0) continue;
        unsigned a = (qlo > Be) ? (qlo - Be) : 0;
        unsigned bb = qhi - Be; if (bb > segw) bb = segw;
        int r0 = (int)(nlo[e] + (a + K - 1) / K);
        int r1 = (int)(nlo[e] + (bb + K - 1) / K);
        if (r1 <= r0) continue;
        switch (e) {   // wave-uniform branch
            case 0: seg_pass4<4> (srt, lds, 0, r0, r1, lane, wave, redS, redV); break;
            case 1: seg_pass4<5> (srt, lds, 1, r0, r1, lane, wave, redS, redV); break;
            case 2: seg_pass4<6> (srt, lds, 2, r0, r1, lane, wave, redS, redV); break;
            case 3: seg_pass4<7> (srt, lds, 3, r0, r1, lane, wave, redS, redV); break;
            case 4: seg_pass4<8> (srt, lds, 4, r0, r1, lane, wave, redS, redV); break;
            case 5: seg_pass4<9> (srt, lds, 5, r0, r1, lane, wave, redS, redV); break;
            case 6: seg_pass4<10>(srt, lds, 6, r0, r1, lane, wave, redS, redV); break;
        }
    }
    __syncthreads();

    if (tid < 28) {   // reduce 8 wave-slots per (e, dl)
        int e  = tid >> 2;
        int dl = tid & 3;
        float s = redS[tid][0];
        int  vv = redV[tid][0];
#pragma unroll
        for (int w2 = 1; w2 < 8; ++w2) {
            float os = redS[tid][w2];
            int   ov = redV[tid][w2];
            if (os > s || (os == s && ov < vv)) { s = os; vv = ov; }
        }
        int lg = l0 + dl;
        int k = e + MINL;
        bool viable = (lg + k - 1) < len;
        float sn = s / (float)k;   // normalize winner only (bit-same as ref a/k)
        int o = (half * BB * LL + b * 64 + lg) * EE + e;
        val[o] = viable ? sn : NEG;
        voc[o] = viable ? vv : 0;  // ref argmax of all-NEG = 0
    }
}

// ---------------------------------------------------------------------------
// Per-b: merge the two v-halves slot-wise (tie -> smaller voc = smaller v),
// then flat argmax over the 448 (l,e) slots (min flat index on ties),
// any_matched = merged max > THRESH. Outputs written as float32 values.
__global__ __launch_bounds__(512) void k_final(const float* __restrict__ val,
                                               const int* __restrict__ voc,
                                               float* __restrict__ out) {
    __shared__ float sS[8];
    __shared__ int   sI[8];
    __shared__ int   sV[8];
    __shared__ int   sA[8];
    int b = blockIdx.x;
    int t = threadIdx.x;
    float s = -3e38f;
    int idx = 1 << 30;
    int vc = 0;
    int any = 0;
    if (t < LL * EE) {
        int o0 = b * LL * EE + t;
        int o1 = BB * LL * EE + o0;
        float s0 = val[o0], s1 = val[o1];
        int   v0 = voc[o0], v1 = voc[o1];
        bool sel = (s1 > s0) || (s1 == s0 && v1 < v0);
        s  = sel ? s1 : s0;
        vc = sel ? v1 : v0;
        idx = t;
        any = (s > TH) ? 1 : 0;
    }
#pragma unroll
    for (int off = 32; off > 0; off >>= 1) {
        float os = __shfl_down(s, off, 64);
        int   oi = __shfl_down(idx, off, 64);
        int   ov = __shfl_down(vc, off, 64);
        int   oa = __shfl_down(any, off, 64);
        if (os > s || (os == s && oi < idx)) { s = os; idx = oi; vc = ov; }
        any |= oa;
    }
    int w = t >> 6, lane = t & 63;
    if (lane == 0) { sS[w] = s; sI[w] = idx; sV[w] = vc; sA[w] = any; }
    __syncthreads();
    if (t == 0) {
        for (int w2 = 1; w2 < 8; ++w2) {
            float os = sS[w2];
            int   oi = sI[w2];
            if (os > s || (os == s && oi < idx)) { s = os; idx = oi; vc = sV[w2]; }
            any |= sA[w2];
        }
        int start = idx / EE;
        int e = idx - start * EE;
        int end = e + start + MINL - 1;
        out[b]      = s;
        out[16 + b] = (float)start;
        out[32 + b] = (float)end;
        out[48 + b] = any ? 1.0f : 0.0f;
        out[64 + b] = (float)vc;
    }
}

// ---------------------------------------------------------------------------
extern "C" void kernel_launch(void* const* d_in, const int* in_sizes, int n_in,
                              void* d_out, int out_size, void* d_ws, size_t ws_size,
                              hipStream_t stream) {
    const float* x       = (const float*)d_in[0];   // [16][64][60]
    const float* uf      = (const float*)d_in[1];   // [600][60]
    const float* W       = (const float*)d_in[2];   // [60][256]
    const int*   lengths = (const int*)d_in[3];     // [16]
    const int*   seg     = (const int*)d_in[4];     // [10000][10]
    const int*   vlen    = (const int*)d_in[5];     // [10000]
    float* out = (float*)d_out;
    float* ws  = (float*)d_ws;

    float*        unT = ws + UNT_OFF;
    float*        wnT = ws + WNT_OFF;
    float*        sim = ws + SIM_OFF;
    unsigned int* cnt = (unsigned int*)(ws + CNT_OFF);
    unsigned int* srt = (unsigned int*)(ws + SRT_OFF);
    float*        val = ws + VAL_OFF;
    int*          voc = (int*)(ws + VOC_OFF);

    hipMemsetAsync(cnt, 0, 8 * sizeof(unsigned int), stream);  // bucket cursors
    k_prep<<<446, 256, 0, stream>>>(seg, vlen, x, uf, W, cnt, srt, unT, wnT);
    k_sim<<<512, 320, 0, stream>>>(unT, wnT, lengths, sim);
    k_score<<<512, 512, 0, stream>>>(sim, srt, cnt, lengths, val, voc);
    k_final<<<BB, 512, 0, stream>>>(val, voc, out);
}